// Round 1
// baseline (372.793 us; speedup 1.0000x reference)
//
#include <hip/hip_runtime.h>
#include <math.h>

namespace {

constexpr int B = 8, L = 101, DIM = 1024, H = 8, DH = 128, MF = 621;
constexpr int BL = B * L;   // 808
constexpr int BH = B * H;   // 64

constexpr float DN    = 0.29730177875068026f;  // 128^-0.25 = 2^-1.75
constexpr float RATIO = 0.04012861672f;        // 621^-0.5
constexpr float EPS   = 1e-4f;

// Static geometry (IMG=10, MAXD=4, K=7, 49 neighbors)
__device__ __forceinline__ void geom(int l, int k, int& diff, bool& valid, int& pos) {
  int dxk = (k % 7) - 3, dyk = (k / 7) - 3;
  int xo = (l < 100) ? (l % 10) : 0;
  int yo = (l < 100) ? (l / 10) : 10;
  int xp = dxk + xo, yp = dyk + yo;
  int df = (dxk < 0 ? -dxk : dxk) + (dyk < 0 ? -dyk : dyk);
  valid = (xp >= 0) && (xp < 10) && (yp >= 0) && (yp < 10) && (df < 4);
  diff = valid ? df : 4;
  pos = l + dxk + 10 * dyk;   // OFFSETS[k] = dx + 10*dy
}

// ---------- C[M][1024] = A[M][1024] @ W[1024][1024]^T + bias ----------
__global__ __launch_bounds__(256) void gemm_bias(const float* __restrict__ A,
                                                 const float* __restrict__ W,
                                                 const float* __restrict__ bias,
                                                 float* __restrict__ C, int M) {
  constexpr int TILE = 64, KC = 16, N = 1024, K = 1024;
  __shared__ float As[KC][TILE + 4];
  __shared__ float Bs[KC][TILE + 4];
  const int tid = threadIdx.x;
  const int tx = tid & 15, ty = tid >> 4;
  const int rowBase = blockIdx.y * TILE, colBase = blockIdx.x * TILE;
  const int lrow = tid >> 2, lk4 = (tid & 3) << 2;
  const bool aOK = (rowBase + lrow) < M;
  const float* Arow = A + (size_t)(rowBase + lrow) * K;
  const float* Wrow = W + (size_t)(colBase + lrow) * K;
  float acc[4][4] = {};
  for (int k0 = 0; k0 < K; k0 += KC) {
    float4 a4 = aOK ? *(const float4*)(Arow + k0 + lk4) : make_float4(0.f, 0.f, 0.f, 0.f);
    float4 b4 = *(const float4*)(Wrow + k0 + lk4);
    __syncthreads();
    As[lk4 + 0][lrow] = a4.x; As[lk4 + 1][lrow] = a4.y;
    As[lk4 + 2][lrow] = a4.z; As[lk4 + 3][lrow] = a4.w;
    Bs[lk4 + 0][lrow] = b4.x; Bs[lk4 + 1][lrow] = b4.y;
    Bs[lk4 + 2][lrow] = b4.z; Bs[lk4 + 3][lrow] = b4.w;
    __syncthreads();
#pragma unroll
    for (int kk = 0; kk < KC; ++kk) {
      float4 av = *(const float4*)&As[kk][ty << 2];
      float4 bv = *(const float4*)&Bs[kk][tx << 2];
      float a[4] = {av.x, av.y, av.z, av.w};
      float b[4] = {bv.x, bv.y, bv.z, bv.w};
#pragma unroll
      for (int i = 0; i < 4; ++i)
#pragma unroll
        for (int j = 0; j < 4; ++j) acc[i][j] += a[i] * b[j];
    }
  }
  const int col = colBase + (tx << 2);
  float4 bb = *(const float4*)(bias + col);
#pragma unroll
  for (int i = 0; i < 4; ++i) {
    int r = rowBase + (ty << 2) + i;
    if (r < M) {
      float4 o = make_float4(acc[i][0] + bb.x, acc[i][1] + bb.y,
                             acc[i][2] + bb.z, acc[i][3] + bb.w);
      *(float4*)(C + (size_t)r * N + col) = o;
    }
  }
}

// ---------- rf (5x621), mde, rfm = rf - mde (rows 0..3), denom (101x621) ----------
__global__ __launch_bounds__(256) void rf_denom_kernel(const float* __restrict__ rpe,
                                                       const float* __restrict__ proj,
                                                       float* __restrict__ mde,
                                                       float* __restrict__ rfm,
                                                       float* __restrict__ denom) {
  __shared__ float rp[5][DH];
  __shared__ float ddl[5][MF];
  __shared__ float diag5[5];
  __shared__ float red[256];
  __shared__ float cnt[L][4];
  const int tid = threadIdx.x;
  for (int idx = tid; idx < 5 * DH; idx += 256) rp[idx / DH][idx % DH] = rpe[idx] * DN;
  __syncthreads();
  if (tid < 5) {
    float s = 0.f;
    for (int d = 0; d < DH; ++d) s += rp[tid][d] * rp[tid][d];
    diag5[tid] = 0.5f * s;
  }
  for (int idx = tid; idx < 5 * MF; idx += 256) {
    int r = idx / MF, j = idx % MF;
    const float4* pj = (const float4*)(proj + (size_t)j * DH);
    float s = 0.f;
#pragma unroll 4
    for (int c = 0; c < DH / 4; ++c) {
      float4 p = pj[c];
      s += rp[r][c * 4 + 0] * p.x + rp[r][c * 4 + 1] * p.y +
           rp[r][c * 4 + 2] * p.z + rp[r][c * 4 + 3] * p.w;
    }
    ddl[r][j] = s;
  }
  __syncthreads();
  float m = -INFINITY;
  for (int idx = tid; idx < 5 * MF; idx += 256) m = fmaxf(m, ddl[idx / MF][idx % MF]);
  red[tid] = m;
  __syncthreads();
  for (int s = 128; s > 0; s >>= 1) {
    if (tid < s) red[tid] = fmaxf(red[tid], red[tid + s]);
    __syncthreads();
  }
  const float mx = red[0];
  for (int idx = tid; idx < 5 * MF; idx += 256) {
    int r = idx / MF, j = idx % MF;
    ddl[r][j] = RATIO * (__expf(ddl[r][j] - diag5[r] - mx) + EPS);
  }
  __syncthreads();
  for (int j = tid; j < MF; j += 256) mde[j] = ddl[4][j];
  for (int idx = tid; idx < 4 * MF; idx += 256) {
    int r = idx / MF, j = idx % MF;
    float v = ddl[r][j] - ddl[4][j];
    ddl[r][j] = v;   // rows 0..3 become rfm; row 4 stays mde
    rfm[idx] = v;
  }
  for (int l = tid; l < L; l += 256) {
    float c0 = 0, c1 = 0, c2 = 0, c3 = 0;
    for (int k = 0; k < 49; ++k) {
      int diff, pos; bool valid;
      geom(l, k, diff, valid, pos);
      if (valid) {
        if (diff == 0) c0 += 1.f;
        else if (diff == 1) c1 += 1.f;
        else if (diff == 2) c2 += 1.f;
        else c3 += 1.f;
      }
    }
    cnt[l][0] = c0; cnt[l][1] = c1; cnt[l][2] = c2; cnt[l][3] = c3;
  }
  __syncthreads();
  for (int idx = tid; idx < L * MF; idx += 256) {
    int l = idx / MF, j = idx % MF;
    denom[idx] = cnt[l][0] * ddl[0][j] + cnt[l][1] * ddl[1][j] +
                 cnt[l][2] * ddl[2][j] + cnt[l][3] * ddl[3][j] +
                 (float)L * ddl[4][j];
  }
}

// ---------- v_sum over L ----------
__global__ void vsum_kernel(const float* __restrict__ v, float* __restrict__ vsum) {
  const int bh = blockIdx.x, d = threadIdx.x;
  const int b = bh / H, h = bh % H;
  const float* base = v + (size_t)(b * L) * DIM + h * DH + d;
  float s = 0.f;
  for (int l = 0; l < L; ++l) s += base[(size_t)l * DIM];
  vsum[bh * DH + d] = s;
}

// ---------- fused feature-map + relative attention ----------
__global__ __launch_bounds__(256) void attn_kernel(const float* __restrict__ q,
                                                   const float* __restrict__ v,
                                                   const float* __restrict__ proj,
                                                   const float* __restrict__ mde,
                                                   const float* __restrict__ rfm,
                                                   const float* __restrict__ denom,
                                                   const float* __restrict__ vsum,
                                                   float* __restrict__ attn) {
  constexpr int TL = 8;
  __shared__ float qs[TL][DH];
  __shared__ float dd[TL][MF + 3];
  __shared__ float diagl[TL], mxl[TL];
  __shared__ float part[4][TL][6];
  __shared__ float acc6[TL][6];
  __shared__ float wgt[TL][49];
  __shared__ int   posi[TL][49];
  const int tid = threadIdx.x;
  const int lt = blockIdx.x, bh = blockIdx.y;
  const int b = bh / H, h = bh % H;
  const int l0 = lt * TL;
  // stage q * dn
  for (int idx = tid; idx < TL * DH; idx += 256) {
    int i = idx / DH, d = idx % DH;
    int l = l0 + i;
    qs[i][d] = (l < L) ? q[(size_t)(b * L + l) * DIM + h * DH + d] * DN : 0.f;
  }
  __syncthreads();
  if (tid < TL) {
    float s = 0.f;
    for (int d = 0; d < DH; ++d) s += qs[tid][d] * qs[tid][d];
    diagl[tid] = 0.5f * s;
  }
  // dd[i][j] = qs[i] . proj[j]  — c outer so qs chunks live in regs
  {
    float p0[TL] = {}, p1[TL] = {}, p2[TL] = {};
    const int j0 = tid, j1 = tid + 256, j2 = tid + 512;
#pragma unroll 4
    for (int c = 0; c < DH / 4; ++c) {
      float4 qc[TL];
#pragma unroll
      for (int i = 0; i < TL; ++i) qc[i] = *(const float4*)&qs[i][c << 2];
      {
        float4 pr = *(const float4*)(proj + (size_t)j0 * DH + (c << 2));
#pragma unroll
        for (int i = 0; i < TL; ++i)
          p0[i] += qc[i].x * pr.x + qc[i].y * pr.y + qc[i].z * pr.z + qc[i].w * pr.w;
      }
      {
        float4 pr = *(const float4*)(proj + (size_t)j1 * DH + (c << 2));
#pragma unroll
        for (int i = 0; i < TL; ++i)
          p1[i] += qc[i].x * pr.x + qc[i].y * pr.y + qc[i].z * pr.z + qc[i].w * pr.w;
      }
      if (j2 < MF) {
        float4 pr = *(const float4*)(proj + (size_t)j2 * DH + (c << 2));
#pragma unroll
        for (int i = 0; i < TL; ++i)
          p2[i] += qc[i].x * pr.x + qc[i].y * pr.y + qc[i].z * pr.z + qc[i].w * pr.w;
      }
    }
#pragma unroll
    for (int i = 0; i < TL; ++i) {
      dd[i][j0] = p0[i];
      dd[i][j1] = p1[i];
      if (j2 < MF) dd[i][j2] = p2[i];
    }
  }
  __syncthreads();
  // per-row max (wave w owns rows 2w, 2w+1)
  const int wv = tid >> 6, lane = tid & 63;
  for (int i = wv * 2; i < wv * 2 + 2; ++i) {
    float m = -INFINITY;
    for (int j = lane; j < MF; j += 64) m = fmaxf(m, dd[i][j]);
#pragma unroll
    for (int o = 32; o > 0; o >>= 1) m = fmaxf(m, __shfl_xor(m, o, 64));
    if (lane == 0) mxl[i] = m;
  }
  __syncthreads();
  // six weighted sums per row: q_dot[0..3], D, q_md
  for (int i = 0; i < TL; ++i) {
    int lg = l0 + i; if (lg >= L) lg = 0;
    const float* drow = denom + (size_t)lg * MF;
    float s0 = 0, s1 = 0, s2 = 0, s3 = 0, sD = 0, sM = 0;
    const float dg = diagl[i], mxv = mxl[i];
    for (int j = tid; j < MF; j += 256) {
      float qf = RATIO * (__expf(dd[i][j] - dg - mxv) + EPS);
      s0 += qf * rfm[j];
      s1 += qf * rfm[MF + j];
      s2 += qf * rfm[2 * MF + j];
      s3 += qf * rfm[3 * MF + j];
      sD += qf * drow[j];
      sM += qf * mde[j];
    }
#pragma unroll
    for (int o = 32; o > 0; o >>= 1) {
      s0 += __shfl_xor(s0, o, 64); s1 += __shfl_xor(s1, o, 64);
      s2 += __shfl_xor(s2, o, 64); s3 += __shfl_xor(s3, o, 64);
      sD += __shfl_xor(sD, o, 64); sM += __shfl_xor(sM, o, 64);
    }
    if (lane == 0) {
      part[wv][i][0] = s0; part[wv][i][1] = s1; part[wv][i][2] = s2;
      part[wv][i][3] = s3; part[wv][i][4] = sD; part[wv][i][5] = sM;
    }
  }
  __syncthreads();
  if (tid < TL * 6) {
    int i = tid / 6, c = tid % 6;
    acc6[i][c] = part[0][i][c] + part[1][i][c] + part[2][i][c] + part[3][i][c];
  }
  __syncthreads();
  // neighbor weights
  for (int idx = tid; idx < TL * 49; idx += 256) {
    int i = idx / 49, k = idx % 49;
    int l = l0 + i;
    float w = 0.f; int p = 0;
    if (l < L) {
      int diff, pos; bool valid;
      geom(l, k, diff, valid, pos);
      if (valid && pos >= 0 && pos < L) { w = acc6[i][diff]; p = pos; }
    }
    wgt[i][k] = w; posi[i][k] = p;
  }
  __syncthreads();
  // output: out[d] = (q_md*vsum[d] + sum_k w_k * v[pos_k][d]) / D
  const int sub = tid >> 7, d = tid & 127;
  for (int i = sub; i < TL; i += 2) {
    int l = l0 + i;
    if (l >= L) break;
    float o = acc6[i][5] * vsum[bh * DH + d];
    for (int k = 0; k < 49; ++k) {
      float w = wgt[i][k];
      if (w != 0.f) o += w * v[(size_t)(b * L + posi[i][k]) * DIM + h * DH + d];
    }
    attn[(size_t)(b * L + l) * DIM + h * DH + d] = o / acc6[i][4];
  }
}

}  // namespace

extern "C" void kernel_launch(void* const* d_in, const int* in_sizes, int n_in,
                              void* d_out, int out_size, void* d_ws, size_t ws_size,
                              hipStream_t stream) {
  const float* x    = (const float*)d_in[0];
  const float* Wq   = (const float*)d_in[1];
  const float* bq   = (const float*)d_in[2];
  const float* Wv   = (const float*)d_in[3];
  const float* bv   = (const float*)d_in[4];
  const float* rpe  = (const float*)d_in[5];
  const float* proj = (const float*)d_in[6];
  const float* Wo   = (const float*)d_in[7];
  const float* bo   = (const float*)d_in[8];

  float* ws    = (float*)d_ws;
  float* q     = ws;                  // 827392
  float* v     = q + 827392;          // 827392
  float* attn  = v + 827392;          // 827392
  float* vsum  = attn + 827392;       // 8192
  float* mde   = vsum + 8192;         // 640 (621 used)
  float* rfm   = mde + 640;           // 2560 (2484 used)
  float* denom = rfm + 2560;          // 62784 (62721 used)

  dim3 gG(16, 13);  // 1024/64 cols, ceil(808/64) rows
  gemm_bias<<<gG, 256, 0, stream>>>(x, Wq, bq, q, BL);
  gemm_bias<<<gG, 256, 0, stream>>>(x, Wv, bv, v, BL);
  rf_denom_kernel<<<1, 256, 0, stream>>>(rpe, proj, mde, rfm, denom);
  vsum_kernel<<<BH, DH, 0, stream>>>(v, vsum);
  attn_kernel<<<dim3(13, BH), 256, 0, stream>>>(q, v, proj, mde, rfm, denom, vsum, attn);
  gemm_bias<<<gG, 256, 0, stream>>>(attn, Wo, bo, (float*)d_out, BL);
}

// Round 2
// 214.777 us; speedup vs baseline: 1.7357x; 1.7357x over previous
//
#include <hip/hip_runtime.h>
#include <math.h>

namespace {

typedef __bf16 bf16_t;
typedef bf16_t bf16x8 __attribute__((ext_vector_type(8)));
typedef bf16_t bf16x4 __attribute__((ext_vector_type(4)));
typedef float f32x4 __attribute__((ext_vector_type(4)));

constexpr int B = 8, L = 101, DIM = 1024, H = 8, DH = 128, MF = 621, MFP = 640;
constexpr int BL = B * L;   // 808
constexpr int BH = B * H;   // 64
constexpr int RR = BL * H;  // 6464 rows of (b,l,h)

constexpr float DN    = 0.29730177875068026f;   // 128^-0.25
constexpr float DN2   = 0.08838834764831845f;   // 128^-0.5
constexpr float RATIO = 0.04012861672f;         // 621^-0.5
constexpr float EPS   = 1e-4f;

__device__ __forceinline__ f32x4 mfma16(bf16x8 a, bf16x8 b, f32x4 c) {
  return __builtin_amdgcn_mfma_f32_16x16x32_bf16(a, b, c, 0, 0, 0);
}

__device__ __forceinline__ void split2(float f, bf16_t& h, bf16_t& l) {
  h = (bf16_t)f;
  l = (bf16_t)(f - (float)h);
}

// ---------- f32 -> (hi,lo) bf16 split, 4 elems/thread ----------
__global__ __launch_bounds__(256) void split_kernel(const float* __restrict__ src,
                                                    bf16_t* __restrict__ dh,
                                                    bf16_t* __restrict__ dl, int n4) {
  int u = blockIdx.x * 256 + threadIdx.x;
  if (u >= n4) return;
  float4 f = ((const float4*)src)[u];
  bf16x4 hv, lv;
  bf16_t h, l;
  split2(f.x, h, l); hv[0] = h; lv[0] = l;
  split2(f.y, h, l); hv[1] = h; lv[1] = l;
  split2(f.z, h, l); hv[2] = h; lv[2] = l;
  split2(f.w, h, l); hv[3] = h; lv[3] = l;
  *(bf16x4*)(dh + (size_t)u * 4) = hv;
  *(bf16x4*)(dl + (size_t)u * 4) = lv;
}

// ---------- proj*DN -> split, padded to 640 rows with zeros ----------
__global__ __launch_bounds__(256) void split_proj_kernel(const float* __restrict__ proj,
                                                         bf16_t* __restrict__ ph,
                                                         bf16_t* __restrict__ pl) {
  int u = blockIdx.x * 256 + threadIdx.x;   // float4 units, 640*32
  if (u >= MFP * 32) return;
  int j = u >> 5;
  bf16x4 hv = {}, lv = {};
  if (j < MF) {
    float4 f = ((const float4*)proj)[u];
    bf16_t h, l;
    split2(f.x * DN, h, l); hv[0] = h; lv[0] = l;
    split2(f.y * DN, h, l); hv[1] = h; lv[1] = l;
    split2(f.z * DN, h, l); hv[2] = h; lv[2] = l;
    split2(f.w * DN, h, l); hv[3] = h; lv[3] = l;
  }
  *(bf16x4*)(ph + (size_t)u * 4) = hv;
  *(bf16x4*)(pl + (size_t)u * 4) = lv;
}

// ---------- split-bf16 MFMA GEMM: C[M][1024] = (Ah+Al)[M][1024] @ (Bh+Bl)[1024][1024]^T + bias ----------
// MODE 0: write f32 Cf.  MODE 1: write bf16 split Ch/Cl.
template<int MODE>
__global__ __launch_bounds__(256) void gemm_split(const bf16_t* __restrict__ Ah,
                                                  const bf16_t* __restrict__ Al,
                                                  const bf16_t* __restrict__ Bh,
                                                  const bf16_t* __restrict__ Bl,
                                                  const float* __restrict__ bias,
                                                  float* __restrict__ Cf,
                                                  bf16_t* __restrict__ Ch,
                                                  bf16_t* __restrict__ Cl, int M) {
  constexpr int K = 1024, N = 1024;
  const int tid = threadIdx.x;
  const int w = tid >> 6, lane = tid & 63;
  const int wr = w >> 1, wc = w & 1;
  const int l15 = lane & 15, l4 = lane >> 4;
  const int rowBase = blockIdx.y * 64 + wr * 32;
  const int colBase = blockIdx.x * 64 + wc * 32;
  int ra0 = rowBase + l15;      if (ra0 >= M) ra0 = M - 1;
  int ra1 = rowBase + 16 + l15; if (ra1 >= M) ra1 = M - 1;
  const size_t a0 = (size_t)ra0 * K + l4 * 8;
  const size_t a1 = (size_t)ra1 * K + l4 * 8;
  const size_t b0 = (size_t)(colBase + l15) * K + l4 * 8;
  const size_t b1 = (size_t)(colBase + 16 + l15) * K + l4 * 8;
  f32x4 acc[2][2] = {};
#pragma unroll 4
  for (int k0 = 0; k0 < K; k0 += 32) {
    bf16x8 a0h = *(const bf16x8*)(Ah + a0 + k0);
    bf16x8 a0l = *(const bf16x8*)(Al + a0 + k0);
    bf16x8 a1h = *(const bf16x8*)(Ah + a1 + k0);
    bf16x8 a1l = *(const bf16x8*)(Al + a1 + k0);
    bf16x8 b0h = *(const bf16x8*)(Bh + b0 + k0);
    bf16x8 b0l = *(const bf16x8*)(Bl + b0 + k0);
    bf16x8 b1h = *(const bf16x8*)(Bh + b1 + k0);
    bf16x8 b1l = *(const bf16x8*)(Bl + b1 + k0);
    acc[0][0] = mfma16(a0h, b0h, acc[0][0]);
    acc[0][0] = mfma16(a0l, b0h, acc[0][0]);
    acc[0][0] = mfma16(a0h, b0l, acc[0][0]);
    acc[0][1] = mfma16(a0h, b1h, acc[0][1]);
    acc[0][1] = mfma16(a0l, b1h, acc[0][1]);
    acc[0][1] = mfma16(a0h, b1l, acc[0][1]);
    acc[1][0] = mfma16(a1h, b0h, acc[1][0]);
    acc[1][0] = mfma16(a1l, b0h, acc[1][0]);
    acc[1][0] = mfma16(a1h, b0l, acc[1][0]);
    acc[1][1] = mfma16(a1h, b1h, acc[1][1]);
    acc[1][1] = mfma16(a1l, b1h, acc[1][1]);
    acc[1][1] = mfma16(a1h, b1l, acc[1][1]);
  }
#pragma unroll
  for (int ni = 0; ni < 2; ++ni) {
    const int col = colBase + ni * 16 + l15;
    const float bv = bias[col];
#pragma unroll
    for (int mi = 0; mi < 2; ++mi) {
#pragma unroll
      for (int r2 = 0; r2 < 4; ++r2) {
        const int row = rowBase + mi * 16 + l4 * 4 + r2;
        if (row < M) {
          float val = acc[mi][ni][r2] + bv;
          if (MODE == 0) {
            Cf[(size_t)row * N + col] = val;
          } else {
            bf16_t h, lo; split2(val, h, lo);
            Ch[(size_t)row * N + col] = h;
            Cl[(size_t)row * N + col] = lo;
          }
        }
      }
    }
  }
}

// ---------- rf features: rfm[0..3][640]=rf-mde, rfm[4][640]=mde (zero-padded) ----------
__global__ __launch_bounds__(256) void rf_kernel(const float* __restrict__ rpe,
                                                 const float* __restrict__ proj,
                                                 float* __restrict__ rfm) {
  __shared__ float rp[5][DH];
  __shared__ float ddl[5][MF];
  __shared__ float diag5[5];
  __shared__ float red[256];
  const int tid = threadIdx.x;
  for (int i = tid; i < 5 * DH; i += 256) rp[i / DH][i % DH] = rpe[i] * DN;
  __syncthreads();
  if (tid < 5) {
    float s = 0.f;
    for (int d = 0; d < DH; ++d) s += rp[tid][d] * rp[tid][d];
    diag5[tid] = 0.5f * s;
  }
  for (int i = tid; i < 5 * MF; i += 256) {
    int r = i / MF, j = i % MF;
    const float4* pj = (const float4*)(proj + (size_t)j * DH);
    float s = 0.f;
#pragma unroll 4
    for (int c = 0; c < DH / 4; ++c) {
      float4 p = pj[c];
      s += rp[r][4 * c] * p.x + rp[r][4 * c + 1] * p.y +
           rp[r][4 * c + 2] * p.z + rp[r][4 * c + 3] * p.w;
    }
    ddl[r][j] = s;
  }
  __syncthreads();
  float m = -3.4e38f;
  for (int i = tid; i < 5 * MF; i += 256) m = fmaxf(m, ddl[i / MF][i % MF]);
  red[tid] = m;
  __syncthreads();
  for (int s2 = 128; s2 > 0; s2 >>= 1) {
    if (tid < s2) red[tid] = fmaxf(red[tid], red[tid + s2]);
    __syncthreads();
  }
  const float mx = red[0];
  for (int i = tid; i < 5 * MF; i += 256) {
    int r = i / MF, j = i % MF;
    ddl[r][j] = RATIO * (__expf(ddl[r][j] - diag5[r] - mx) + EPS);
  }
  __syncthreads();
  for (int i = tid; i < 5 * MFP; i += 256) {
    int r = i / MFP, j = i % MFP;
    float val = 0.f;
    if (j < MF) val = (r < 4) ? (ddl[r][j] - ddl[4][j]) : ddl[4][j];
    rfm[i] = val;
  }
}

// ---------- fused dd-GEMM + rowmax + exp + 5 reductions ----------
// block: 32 rows x 640 cols, 4 waves each owning 160 cols. fd[r][0..3]=q_dot, fd[r][4]=sM.
__global__ __launch_bounds__(256) void qf_kernel(const bf16_t* __restrict__ qh,
                                                 const bf16_t* __restrict__ ql,
                                                 const bf16_t* __restrict__ ph,
                                                 const bf16_t* __restrict__ pl,
                                                 const float* __restrict__ rfm,
                                                 float* __restrict__ fd) {
  __shared__ float rfs[5][MFP];
  __shared__ float diag[32];
  __shared__ float mxs[4][32];
  __shared__ float mxAll[32];
  __shared__ float sred[4][32][5];
  const int tid = threadIdx.x;
  const int r0 = blockIdx.x * 32;
  for (int i = tid; i < 5 * MFP; i += 256) rfs[i / MFP][i % MFP] = rfm[i];
  {  // diag[row] = 0.5*DN^2 * |q_row|^2
    const int row = tid >> 3, ch = tid & 7;
    const size_t base = (size_t)(r0 + row) * DH + ch * 16;
    float s = 0.f;
#pragma unroll
    for (int t = 0; t < 2; ++t) {
      bf16x8 vh = *(const bf16x8*)(qh + base + t * 8);
      bf16x8 vl = *(const bf16x8*)(ql + base + t * 8);
#pragma unroll
      for (int e = 0; e < 8; ++e) {
        float f = (float)vh[e] + (float)vl[e];
        s += f * f;
      }
    }
    s += __shfl_xor(s, 1, 64); s += __shfl_xor(s, 2, 64); s += __shfl_xor(s, 4, 64);
    if (ch == 0) diag[row] = (0.5f * DN2) * s;
  }
  const int w = tid >> 6, lane = tid & 63, l15 = lane & 15, l4 = lane >> 4;
  const int nb = w * 160;
  f32x4 acc[2][10] = {};
  const size_t a0 = (size_t)(r0 + l15) * DH + l4 * 8;
  const size_t a1 = a0 + (size_t)16 * DH;
#pragma unroll
  for (int ks = 0; ks < 4; ++ks) {
    const int k0 = ks * 32;
    bf16x8 a0h = *(const bf16x8*)(qh + a0 + k0);
    bf16x8 a0l = *(const bf16x8*)(ql + a0 + k0);
    bf16x8 a1h = *(const bf16x8*)(qh + a1 + k0);
    bf16x8 a1l = *(const bf16x8*)(ql + a1 + k0);
#pragma unroll
    for (int ni = 0; ni < 10; ++ni) {
      const size_t bo = (size_t)(nb + ni * 16 + l15) * DH + k0 + l4 * 8;
      bf16x8 bh = *(const bf16x8*)(ph + bo);
      bf16x8 bl = *(const bf16x8*)(pl + bo);
      acc[0][ni] = mfma16(a0h, bh, acc[0][ni]);
      acc[0][ni] = mfma16(a0l, bh, acc[0][ni]);
      acc[0][ni] = mfma16(a0h, bl, acc[0][ni]);
      acc[1][ni] = mfma16(a1h, bh, acc[1][ni]);
      acc[1][ni] = mfma16(a1l, bh, acc[1][ni]);
      acc[1][ni] = mfma16(a1h, bl, acc[1][ni]);
    }
  }
  __syncthreads();
  // per-row max over this wave's 160 cols (mask padded cols)
  float pm[2][4];
#pragma unroll
  for (int mi = 0; mi < 2; ++mi)
#pragma unroll
    for (int r2 = 0; r2 < 4; ++r2) {
      float m = -3.4e38f;
#pragma unroll
      for (int ni = 0; ni < 10; ++ni) {
        const int col = nb + ni * 16 + l15;
        float vv = (col < MF) ? acc[mi][ni][r2] : -3.4e38f;
        m = fmaxf(m, vv);
      }
      pm[mi][r2] = m;
    }
#pragma unroll
  for (int mask = 1; mask <= 8; mask <<= 1)
#pragma unroll
    for (int mi = 0; mi < 2; ++mi)
#pragma unroll
      for (int r2 = 0; r2 < 4; ++r2)
        pm[mi][r2] = fmaxf(pm[mi][r2], __shfl_xor(pm[mi][r2], mask, 64));
  if (l15 == 0) {
#pragma unroll
    for (int mi = 0; mi < 2; ++mi)
#pragma unroll
      for (int r2 = 0; r2 < 4; ++r2)
        mxs[w][mi * 16 + l4 * 4 + r2] = pm[mi][r2];
  }
  __syncthreads();
  if (tid < 32)
    mxAll[tid] = fmaxf(fmaxf(mxs[0][tid], mxs[1][tid]), fmaxf(mxs[2][tid], mxs[3][tid]));
  __syncthreads();
  // qf = RATIO*(exp(dd - diag - mx) + EPS); 5 weighted sums
  float s[2][4][5] = {};
#pragma unroll
  for (int mi = 0; mi < 2; ++mi)
#pragma unroll
    for (int r2 = 0; r2 < 4; ++r2) {
      const int row = mi * 16 + l4 * 4 + r2;
      const float sub = diag[row] + mxAll[row];
#pragma unroll
      for (int ni = 0; ni < 10; ++ni) {
        const int col = nb + ni * 16 + l15;
        const float qfv = RATIO * (__expf(acc[mi][ni][r2] - sub) + EPS);
#pragma unroll
        for (int c = 0; c < 5; ++c) s[mi][r2][c] += qfv * rfs[c][col];
      }
    }
#pragma unroll
  for (int mask = 1; mask <= 8; mask <<= 1)
#pragma unroll
    for (int mi = 0; mi < 2; ++mi)
#pragma unroll
      for (int r2 = 0; r2 < 4; ++r2)
#pragma unroll
        for (int c = 0; c < 5; ++c)
          s[mi][r2][c] += __shfl_xor(s[mi][r2][c], mask, 64);
  if (l15 == 0) {
#pragma unroll
    for (int mi = 0; mi < 2; ++mi)
#pragma unroll
      for (int r2 = 0; r2 < 4; ++r2)
#pragma unroll
        for (int c = 0; c < 5; ++c)
          sred[w][mi * 16 + l4 * 4 + r2][c] = s[mi][r2][c];
  }
  __syncthreads();
  if (tid < 160) {
    const int row = tid / 5, c = tid % 5;
    fd[(size_t)(r0 + row) * 8 + c] =
        sred[0][row][c] + sred[1][row][c] + sred[2][row][c] + sred[3][row][c];
  }
}

// ---------- v_sum over L ----------
__global__ void vsum_kernel(const float* __restrict__ v, float* __restrict__ vsum) {
  const int bh = blockIdx.x, d = threadIdx.x;
  const int b = bh / H, h = bh % H;
  const float* base = v + (size_t)(b * L) * DIM + h * DH + d;
  float s = 0.f;
  for (int l = 0; l < L; ++l) s += base[(size_t)l * DIM];
  vsum[bh * DH + d] = s;
}

// ---------- gather + normalize + bf16-split of attn ----------
__global__ __launch_bounds__(256) void out_kernel(const float* __restrict__ fd,
                                                  const float* __restrict__ v,
                                                  const float* __restrict__ vsum,
                                                  bf16_t* __restrict__ attnh,
                                                  bf16_t* __restrict__ attnl) {
  const int tid = threadIdx.x;
  const int sub = tid >> 7, d = tid & 127;
  const int bh = blockIdx.y, b = bh >> 3, h = bh & 7;
  const int l = blockIdx.x * 2 + sub;
  if (l >= L) return;
  const size_t r = (size_t)(b * L + l) * H + h;
  const float q0 = fd[r * 8 + 0], q1 = fd[r * 8 + 1], q2 = fd[r * 8 + 2],
              q3 = fd[r * 8 + 3], sM = fd[r * 8 + 4];
  float o = sM * vsum[bh * DH + d];
  float c0 = 0, c1 = 0, c2 = 0, c3 = 0;
  const int xo = (l < 100) ? (l % 10) : 0;
  const int yo = (l < 100) ? (l / 10) : 10;
#pragma unroll
  for (int k = 0; k < 49; ++k) {
    const int dx = (k % 7) - 3, dy = (k / 7) - 3;
    const int xp = xo + dx, yp = yo + dy;
    const int df = (dx < 0 ? -dx : dx) + (dy < 0 ? -dy : dy);
    if (xp >= 0 && xp < 10 && yp >= 0 && yp < 10 && df < 4) {
      float qq;
      if (df == 0)      { c0 += 1.f; qq = q0; }
      else if (df == 1) { c1 += 1.f; qq = q1; }
      else if (df == 2) { c2 += 1.f; qq = q2; }
      else              { c3 += 1.f; qq = q3; }
      const int pos = l + dx + 10 * dy;
      o += qq * v[(size_t)(b * L + pos) * DIM + h * DH + d];
    }
  }
  const float D = c0 * q0 + c1 * q1 + c2 * q2 + c3 * q3 + (float)L * sM;
  const float val = o / D;
  bf16_t hi, lo; split2(val, hi, lo);
  const size_t oi = (size_t)(b * L + l) * DIM + h * DH + d;
  attnh[oi] = hi;
  attnl[oi] = lo;
}

}  // namespace

extern "C" void kernel_launch(void* const* d_in, const int* in_sizes, int n_in,
                              void* d_out, int out_size, void* d_ws, size_t ws_size,
                              hipStream_t stream) {
  const float* x    = (const float*)d_in[0];
  const float* Wq   = (const float*)d_in[1];
  const float* bq   = (const float*)d_in[2];
  const float* Wv   = (const float*)d_in[3];
  const float* bv   = (const float*)d_in[4];
  const float* rpe  = (const float*)d_in[5];
  const float* proj = (const float*)d_in[6];
  const float* Wo   = (const float*)d_in[7];
  const float* bo   = (const float*)d_in[8];

  char* p = (char*)d_ws;
  auto alloc = [&](size_t bytes) { char* r = p; p += (bytes + 255) & ~255ull; return r; };
  bf16_t* xh  = (bf16_t*)alloc((size_t)BL * DIM * 2);
  bf16_t* xl  = (bf16_t*)alloc((size_t)BL * DIM * 2);
  bf16_t* Wh  = (bf16_t*)alloc((size_t)DIM * DIM * 2);
  bf16_t* Wl  = (bf16_t*)alloc((size_t)DIM * DIM * 2);
  bf16_t* ph  = (bf16_t*)alloc((size_t)MFP * DH * 2);
  bf16_t* pl  = (bf16_t*)alloc((size_t)MFP * DH * 2);
  bf16_t* qh  = (bf16_t*)alloc((size_t)BL * DIM * 2);   // reused as attnh
  bf16_t* ql  = (bf16_t*)alloc((size_t)BL * DIM * 2);   // reused as attnl
  float*  v   = (float*)alloc((size_t)BL * DIM * 4);
  float*  fd  = (float*)alloc((size_t)RR * 8 * 4);
  float*  rfm = (float*)alloc((size_t)5 * MFP * 4);
  float*  vsm = (float*)alloc((size_t)BH * DH * 4);

  const int NX = BL * DIM / 4;       // 206848 float4 units
  const int NW = DIM * DIM / 4;      // 262144

  split_kernel<<<(NX + 255) / 256, 256, 0, stream>>>(x, xh, xl, NX);
  split_proj_kernel<<<(MFP * 32 + 255) / 256, 256, 0, stream>>>(proj, ph, pl);
  rf_kernel<<<1, 256, 0, stream>>>(rpe, proj, rfm);

  split_kernel<<<NW / 256, 256, 0, stream>>>(Wq, Wh, Wl, NW);
  gemm_split<1><<<dim3(16, 13), 256, 0, stream>>>(xh, xl, Wh, Wl, bq, nullptr, qh, ql, BL);

  split_kernel<<<NW / 256, 256, 0, stream>>>(Wv, Wh, Wl, NW);
  gemm_split<0><<<dim3(16, 13), 256, 0, stream>>>(xh, xl, Wh, Wl, bv, v, nullptr, nullptr, BL);

  vsum_kernel<<<BH, DH, 0, stream>>>(v, vsm);
  qf_kernel<<<RR / 32, 256, 0, stream>>>(qh, ql, ph, pl, rfm, fd);
  out_kernel<<<dim3((L + 1) / 2, BH), 256, 0, stream>>>(fd, v, vsm, qh, ql);

  split_kernel<<<NW / 256, 256, 0, stream>>>(Wo, Wh, Wl, NW);
  gemm_split<0><<<dim3(16, 13), 256, 0, stream>>>(qh, ql, Wh, Wl, bo, (float*)d_out, nullptr, nullptr, BL);
}

// Round 3
// 203.593 us; speedup vs baseline: 1.8311x; 1.0549x over previous
//
#include <hip/hip_runtime.h>
#include <math.h>

namespace {

typedef __bf16 bf16_t;
typedef bf16_t bf16x8 __attribute__((ext_vector_type(8)));
typedef bf16_t bf16x4 __attribute__((ext_vector_type(4)));
typedef float f32x4 __attribute__((ext_vector_type(4)));

constexpr int B = 8, L = 101, DIM = 1024, H = 8, DH = 128, MF = 621, MFP = 640;
constexpr int BL = B * L;   // 808
constexpr int BH = B * H;   // 64
constexpr int RR = BL * H;  // 6464 rows of (b,l,h)

constexpr float DN    = 0.29730177875068026f;   // 128^-0.25
constexpr float DN2   = 0.08838834764831845f;   // 128^-0.5
constexpr float RATIO = 0.04012861672f;         // 621^-0.5
constexpr float EPS   = 1e-4f;

constexpr int NX = BL * DIM / 4;   // 206848 float4 units (x)
constexpr int NP = MFP * 32;       // 20480 (proj, padded)
constexpr int NR = 16 * DH / 4;    // 512 (rpe, padded to 16 rows)
constexpr int NW = DIM * DIM / 4;  // 262144 (one W)

__device__ __forceinline__ f32x4 mfma16(bf16x8 a, bf16x8 b, f32x4 c) {
  return __builtin_amdgcn_mfma_f32_16x16x32_bf16(a, b, c, 0, 0, 0);
}

__device__ __forceinline__ void split2(float f, bf16_t& h, bf16_t& l) {
  h = (bf16_t)f;
  l = (bf16_t)(f - (float)h);
}

// ---------- one-shot split of x, proj(*DN, pad 640), rpe(pad 16 rows) ----------
__global__ __launch_bounds__(256) void split_all_kernel(const float* __restrict__ x,
                                                        const float* __restrict__ proj,
                                                        const float* __restrict__ rpe,
                                                        bf16_t* __restrict__ xh, bf16_t* __restrict__ xl,
                                                        bf16_t* __restrict__ ph, bf16_t* __restrict__ pl,
                                                        bf16_t* __restrict__ rh, bf16_t* __restrict__ rl) {
  const int u = blockIdx.x * 256 + threadIdx.x;
  bf16x4 hv = {}, lv = {};
  bf16_t h, l;
  if (u < NX) {
    float4 f = ((const float4*)x)[u];
    split2(f.x, h, l); hv[0] = h; lv[0] = l;
    split2(f.y, h, l); hv[1] = h; lv[1] = l;
    split2(f.z, h, l); hv[2] = h; lv[2] = l;
    split2(f.w, h, l); hv[3] = h; lv[3] = l;
    *(bf16x4*)(xh + (size_t)u * 4) = hv;
    *(bf16x4*)(xl + (size_t)u * 4) = lv;
  } else if (u < NX + NP) {
    const int up = u - NX;
    if ((up >> 5) < MF) {
      float4 f = ((const float4*)proj)[up];
      split2(f.x * DN, h, l); hv[0] = h; lv[0] = l;
      split2(f.y * DN, h, l); hv[1] = h; lv[1] = l;
      split2(f.z * DN, h, l); hv[2] = h; lv[2] = l;
      split2(f.w * DN, h, l); hv[3] = h; lv[3] = l;
    }
    *(bf16x4*)(ph + (size_t)up * 4) = hv;
    *(bf16x4*)(pl + (size_t)up * 4) = lv;
  } else if (u < NX + NP + NR) {
    const int ur = u - NX - NP;
    if (ur < 5 * DH / 4) {   // rows 0..4 real, 5..15 zero
      float4 f = ((const float4*)rpe)[ur];
      split2(f.x, h, l); hv[0] = h; lv[0] = l;
      split2(f.y, h, l); hv[1] = h; lv[1] = l;
      split2(f.z, h, l); hv[2] = h; lv[2] = l;
      split2(f.w, h, l); hv[3] = h; lv[3] = l;
    }
    *(bf16x4*)(rh + (size_t)ur * 4) = hv;
    *(bf16x4*)(rl + (size_t)ur * 4) = lv;
  }
}

// ---------- plain f32 -> split (for W matrices) ----------
__global__ __launch_bounds__(256) void split_kernel(const float* __restrict__ src,
                                                    bf16_t* __restrict__ dh,
                                                    bf16_t* __restrict__ dl, int n4) {
  int u = blockIdx.x * 256 + threadIdx.x;
  if (u >= n4) return;
  float4 f = ((const float4*)src)[u];
  bf16x4 hv, lv;
  bf16_t h, l;
  split2(f.x, h, l); hv[0] = h; lv[0] = l;
  split2(f.y, h, l); hv[1] = h; lv[1] = l;
  split2(f.z, h, l); hv[2] = h; lv[2] = l;
  split2(f.w, h, l); hv[3] = h; lv[3] = l;
  *(bf16x4*)(dh + (size_t)u * 4) = hv;
  *(bf16x4*)(dl + (size_t)u * 4) = lv;
}

// ---------- split-bf16 MFMA GEMM, wave tile 16x32, block tile 32x64 ----------
// MODE 0: write f32 Cf.  MODE 1: write bf16 split Ch/Cl.
template<int MODE>
__global__ __launch_bounds__(256) void gemm_split(const bf16_t* __restrict__ Ah,
                                                  const bf16_t* __restrict__ Al,
                                                  const bf16_t* __restrict__ Bh,
                                                  const bf16_t* __restrict__ Bl,
                                                  const float* __restrict__ bias,
                                                  float* __restrict__ Cf,
                                                  bf16_t* __restrict__ Ch,
                                                  bf16_t* __restrict__ Cl, int M) {
  constexpr int K = 1024, N = 1024;
  const int tid = threadIdx.x;
  const int w = tid >> 6, lane = tid & 63;
  const int wr = w >> 1, wc = w & 1;
  const int l15 = lane & 15, l4 = lane >> 4;
  const int rowBase = blockIdx.y * 32 + wr * 16;
  const int colBase = blockIdx.x * 64 + wc * 32;
  int ra = rowBase + l15; if (ra >= M) ra = M - 1;
  const size_t a0 = (size_t)ra * K + l4 * 8;
  const size_t b0 = (size_t)(colBase + l15) * K + l4 * 8;
  const size_t b1 = b0 + (size_t)16 * K;
  f32x4 acc[2] = {};
#pragma unroll 4
  for (int k0 = 0; k0 < K; k0 += 32) {
    bf16x8 ah = *(const bf16x8*)(Ah + a0 + k0);
    bf16x8 al = *(const bf16x8*)(Al + a0 + k0);
    bf16x8 b0h = *(const bf16x8*)(Bh + b0 + k0);
    bf16x8 b0l = *(const bf16x8*)(Bl + b0 + k0);
    bf16x8 b1h = *(const bf16x8*)(Bh + b1 + k0);
    bf16x8 b1l = *(const bf16x8*)(Bl + b1 + k0);
    acc[0] = mfma16(ah, b0h, acc[0]);
    acc[0] = mfma16(al, b0h, acc[0]);
    acc[0] = mfma16(ah, b0l, acc[0]);
    acc[1] = mfma16(ah, b1h, acc[1]);
    acc[1] = mfma16(al, b1h, acc[1]);
    acc[1] = mfma16(ah, b1l, acc[1]);
  }
#pragma unroll
  for (int ni = 0; ni < 2; ++ni) {
    const int col = colBase + ni * 16 + l15;
    const float bv = bias[col];
#pragma unroll
    for (int r2 = 0; r2 < 4; ++r2) {
      const int row = rowBase + l4 * 4 + r2;
      if (row < M) {
        float val = acc[ni][r2] + bv;
        if (MODE == 0) {
          Cf[(size_t)row * N + col] = val;
        } else {
          bf16_t h, lo; split2(val, h, lo);
          Ch[(size_t)row * N + col] = h;
          Cl[(size_t)row * N + col] = lo;
        }
      }
    }
  }
}

// ---------- fused: dd-GEMM + rf-GEMM + maxes + exp + 5 reductions ----------
// block: 32 q-rows x 640 cols, 4 waves each owning 160 cols.
// fd[r][0..3]=q_dot with (rf-mde), fd[r][4]=sM (qf . mde).
__global__ __launch_bounds__(256) void qf_kernel(const bf16_t* __restrict__ qh,
                                                 const bf16_t* __restrict__ ql,
                                                 const bf16_t* __restrict__ ph,
                                                 const bf16_t* __restrict__ pl,
                                                 const bf16_t* __restrict__ rh,
                                                 const bf16_t* __restrict__ rl,
                                                 const float* __restrict__ rpe,
                                                 float* __restrict__ fd) {
  __shared__ float rfs[5][MFP];
  __shared__ float diag[32];
  __shared__ float diag5v[8];
  __shared__ float mxs[4][32];
  __shared__ float mxAll[32];
  __shared__ float mxrf[4];
  __shared__ float sred[4][32][5];
  const int tid = threadIdx.x;
  const int r0 = blockIdx.x * 32;
  {  // diag[row] = 0.5*DN^2 * |q_row|^2
    const int row = tid >> 3, ch = tid & 7;
    const size_t base = (size_t)(r0 + row) * DH + ch * 16;
    float s = 0.f;
#pragma unroll
    for (int t = 0; t < 2; ++t) {
      bf16x8 vh = *(const bf16x8*)(qh + base + t * 8);
      bf16x8 vl = *(const bf16x8*)(ql + base + t * 8);
#pragma unroll
      for (int e = 0; e < 8; ++e) {
        float f = (float)vh[e] + (float)vl[e];
        s += f * f;
      }
    }
    s += __shfl_xor(s, 1, 64); s += __shfl_xor(s, 2, 64); s += __shfl_xor(s, 4, 64);
    if (ch == 0) diag[row] = (0.5f * DN2) * s;
  }
  if (tid < 40) {  // diag5v[r] = 0.5*DN^2 * |rpe_r|^2
    const int row = tid >> 3, ch = tid & 7;
    float s = 0.f;
#pragma unroll
    for (int e = 0; e < 16; ++e) {
      float f = rpe[row * DH + ch * 16 + e];
      s += f * f;
    }
    s += __shfl_xor(s, 1, 64); s += __shfl_xor(s, 2, 64); s += __shfl_xor(s, 4, 64);
    if (ch == 0) diag5v[row] = (0.5f * DN2) * s;
  }
  const int w = tid >> 6, lane = tid & 63, l15 = lane & 15, l4 = lane >> 4;
  const int nb = w * 160;
  f32x4 acc[2][10] = {};
  f32x4 accr[10] = {};
  const size_t a0 = (size_t)(r0 + l15) * DH + l4 * 8;
  const size_t a1 = a0 + (size_t)16 * DH;
  const size_t ar = (size_t)l15 * DH + l4 * 8;
#pragma unroll
  for (int ks = 0; ks < 4; ++ks) {
    const int k0 = ks * 32;
    bf16x8 a0h = *(const bf16x8*)(qh + a0 + k0);
    bf16x8 a0l = *(const bf16x8*)(ql + a0 + k0);
    bf16x8 a1h = *(const bf16x8*)(qh + a1 + k0);
    bf16x8 a1l = *(const bf16x8*)(ql + a1 + k0);
    bf16x8 arh = *(const bf16x8*)(rh + ar + k0);
    bf16x8 arl = *(const bf16x8*)(rl + ar + k0);
#pragma unroll
    for (int ni = 0; ni < 10; ++ni) {
      const size_t bo = (size_t)(nb + ni * 16 + l15) * DH + k0 + l4 * 8;
      bf16x8 bh = *(const bf16x8*)(ph + bo);
      bf16x8 bl = *(const bf16x8*)(pl + bo);
      acc[0][ni] = mfma16(a0h, bh, acc[0][ni]);
      acc[0][ni] = mfma16(a0l, bh, acc[0][ni]);
      acc[0][ni] = mfma16(a0h, bl, acc[0][ni]);
      acc[1][ni] = mfma16(a1h, bh, acc[1][ni]);
      acc[1][ni] = mfma16(a1l, bh, acc[1][ni]);
      acc[1][ni] = mfma16(a1h, bl, acc[1][ni]);
      accr[ni]   = mfma16(arh, bh, accr[ni]);
      accr[ni]   = mfma16(arl, bh, accr[ni]);
      accr[ni]   = mfma16(arh, bl, accr[ni]);
    }
  }
  // q per-row max over this wave's cols
  float pm[2][4];
#pragma unroll
  for (int mi = 0; mi < 2; ++mi)
#pragma unroll
    for (int r2 = 0; r2 < 4; ++r2) {
      float m = -3.4e38f;
#pragma unroll
      for (int ni = 0; ni < 10; ++ni) {
        const int col = nb + ni * 16 + l15;
        float vv = (col < MF) ? acc[mi][ni][r2] : -3.4e38f;
        m = fmaxf(m, vv);
      }
      pm[mi][r2] = m;
    }
#pragma unroll
  for (int mask = 1; mask <= 8; mask <<= 1)
#pragma unroll
    for (int mi = 0; mi < 2; ++mi)
#pragma unroll
      for (int r2 = 0; r2 < 4; ++r2)
        pm[mi][r2] = fmaxf(pm[mi][r2], __shfl_xor(pm[mi][r2], mask, 64));
  if (l15 == 0) {
#pragma unroll
    for (int mi = 0; mi < 2; ++mi)
#pragma unroll
      for (int r2 = 0; r2 < 4; ++r2)
        mxs[w][mi * 16 + l4 * 4 + r2] = pm[mi][r2];
  }
  // rf global max over rows 0..4, cols<MF
  {
    float m = -3.4e38f;
#pragma unroll
    for (int ni = 0; ni < 10; ++ni) {
      const int col = nb + ni * 16 + l15;
#pragma unroll
      for (int r2 = 0; r2 < 4; ++r2) {
        const int row = l4 * 4 + r2;
        if (row < 5 && col < MF) m = fmaxf(m, accr[ni][r2]);
      }
    }
#pragma unroll
    for (int mask = 1; mask <= 32; mask <<= 1) m = fmaxf(m, __shfl_xor(m, mask, 64));
    if (lane == 0) mxrf[w] = m;
  }
  __syncthreads();
  // rf values (raw) into rfs; also cross-wave q row max
  {
    const float mxR = fmaxf(fmaxf(mxrf[0], mxrf[1]), fmaxf(mxrf[2], mxrf[3]));
#pragma unroll
    for (int ni = 0; ni < 10; ++ni) {
      const int col = nb + ni * 16 + l15;
#pragma unroll
      for (int r2 = 0; r2 < 4; ++r2) {
        const int row = l4 * 4 + r2;
        if (row < 5) {
          float val = (col < MF)
              ? RATIO * (__expf(accr[ni][r2] - diag5v[row] - mxR) + EPS) : 0.f;
          rfs[row][col] = val;
        }
      }
    }
  }
  if (tid < 32)
    mxAll[tid] = fmaxf(fmaxf(mxs[0][tid], mxs[1][tid]), fmaxf(mxs[2][tid], mxs[3][tid]));
  __syncthreads();
  for (int i = tid; i < 4 * MFP; i += 256) rfs[i / MFP][i % MFP] -= rfs[4][i % MFP];
  __syncthreads();
  // qf = RATIO*(exp(dd - diag - mx) + EPS); 5 weighted sums
  float s[2][4][5] = {};
#pragma unroll
  for (int mi = 0; mi < 2; ++mi)
#pragma unroll
    for (int r2 = 0; r2 < 4; ++r2) {
      const int row = mi * 16 + l4 * 4 + r2;
      const float sub = diag[row] + mxAll[row];
#pragma unroll
      for (int ni = 0; ni < 10; ++ni) {
        const int col = nb + ni * 16 + l15;
        const float qfv = RATIO * (__expf(acc[mi][ni][r2] - sub) + EPS);
#pragma unroll
        for (int c = 0; c < 5; ++c) s[mi][r2][c] += qfv * rfs[c][col];
      }
    }
#pragma unroll
  for (int mask = 1; mask <= 8; mask <<= 1)
#pragma unroll
    for (int mi = 0; mi < 2; ++mi)
#pragma unroll
      for (int r2 = 0; r2 < 4; ++r2)
#pragma unroll
        for (int c = 0; c < 5; ++c)
          s[mi][r2][c] += __shfl_xor(s[mi][r2][c], mask, 64);
  if (l15 == 0) {
#pragma unroll
    for (int mi = 0; mi < 2; ++mi)
#pragma unroll
      for (int r2 = 0; r2 < 4; ++r2)
#pragma unroll
        for (int c = 0; c < 5; ++c)
          sred[w][mi * 16 + l4 * 4 + r2][c] = s[mi][r2][c];
  }
  __syncthreads();
  if (tid < 160) {
    const int row = tid / 5, c = tid % 5;
    fd[(size_t)(r0 + row) * 8 + c] =
        sred[0][row][c] + sred[1][row][c] + sred[2][row][c] + sred[3][row][c];
  }
}

// ---------- v_sum over L ----------
__global__ void vsum_kernel(const float* __restrict__ v, float* __restrict__ vsum) {
  const int bh = blockIdx.x, d = threadIdx.x;
  const int b = bh / H, h = bh % H;
  const float* base = v + (size_t)(b * L) * DIM + h * DH + d;
  float s = 0.f;
  for (int l = 0; l < L; ++l) s += base[(size_t)l * DIM];
  vsum[bh * DH + d] = s;
}

// ---------- gather + normalize + bf16-split of attn ----------
__global__ __launch_bounds__(256) void out_kernel(const float* __restrict__ fd,
                                                  const float* __restrict__ v,
                                                  const float* __restrict__ vsum,
                                                  bf16_t* __restrict__ attnh,
                                                  bf16_t* __restrict__ attnl) {
  const int tid = threadIdx.x;
  const int sub = tid >> 7, d = tid & 127;
  const int bh = blockIdx.y, b = bh >> 3, h = bh & 7;
  const int l = blockIdx.x * 2 + sub;
  if (l >= L) return;
  const size_t r = (size_t)(b * L + l) * H + h;
  const float q0 = fd[r * 8 + 0], q1 = fd[r * 8 + 1], q2 = fd[r * 8 + 2],
              q3 = fd[r * 8 + 3], sM = fd[r * 8 + 4];
  float o = sM * vsum[bh * DH + d];
  float c0 = 0, c1 = 0, c2 = 0, c3 = 0;
  const int xo = (l < 100) ? (l % 10) : 0;
  const int yo = (l < 100) ? (l / 10) : 10;
#pragma unroll
  for (int k = 0; k < 49; ++k) {
    const int dx = (k % 7) - 3, dy = (k / 7) - 3;
    const int xp = xo + dx, yp = yo + dy;
    const int df = (dx < 0 ? -dx : dx) + (dy < 0 ? -dy : dy);
    if (xp >= 0 && xp < 10 && yp >= 0 && yp < 10 && df < 4) {
      float qq;
      if (df == 0)      { c0 += 1.f; qq = q0; }
      else if (df == 1) { c1 += 1.f; qq = q1; }
      else if (df == 2) { c2 += 1.f; qq = q2; }
      else              { c3 += 1.f; qq = q3; }
      const int pos = l + dx + 10 * dy;
      o += qq * v[(size_t)(b * L + pos) * DIM + h * DH + d];
    }
  }
  const float D = c0 * q0 + c1 * q1 + c2 * q2 + c3 * q3 + (float)L * sM;
  const float val = o / D;
  bf16_t hi, lo; split2(val, hi, lo);
  const size_t oi = (size_t)(b * L + l) * DIM + h * DH + d;
  attnh[oi] = hi;
  attnl[oi] = lo;
}

}  // namespace

extern "C" void kernel_launch(void* const* d_in, const int* in_sizes, int n_in,
                              void* d_out, int out_size, void* d_ws, size_t ws_size,
                              hipStream_t stream) {
  const float* x    = (const float*)d_in[0];
  const float* Wq   = (const float*)d_in[1];
  const float* bq   = (const float*)d_in[2];
  const float* Wv   = (const float*)d_in[3];
  const float* bv   = (const float*)d_in[4];
  const float* rpe  = (const float*)d_in[5];
  const float* proj = (const float*)d_in[6];
  const float* Wo   = (const float*)d_in[7];
  const float* bo   = (const float*)d_in[8];

  char* p = (char*)d_ws;
  auto alloc = [&](size_t bytes) { char* r = p; p += (bytes + 255) & ~255ull; return r; };
  bf16_t* xh  = (bf16_t*)alloc((size_t)BL * DIM * 2);
  bf16_t* xl  = (bf16_t*)alloc((size_t)BL * DIM * 2);
  bf16_t* Wh  = (bf16_t*)alloc((size_t)DIM * DIM * 2);
  bf16_t* Wl  = (bf16_t*)alloc((size_t)DIM * DIM * 2);
  bf16_t* ph  = (bf16_t*)alloc((size_t)MFP * DH * 2);
  bf16_t* pl  = (bf16_t*)alloc((size_t)MFP * DH * 2);
  bf16_t* rh  = (bf16_t*)alloc((size_t)16 * DH * 2);
  bf16_t* rl  = (bf16_t*)alloc((size_t)16 * DH * 2);
  bf16_t* qh  = (bf16_t*)alloc((size_t)BL * DIM * 2);   // reused as attnh
  bf16_t* ql  = (bf16_t*)alloc((size_t)BL * DIM * 2);   // reused as attnl
  float*  v   = (float*)alloc((size_t)BL * DIM * 4);
  float*  fd  = (float*)alloc((size_t)RR * 8 * 4);
  float*  vsm = (float*)alloc((size_t)BH * DH * 4);

  const int NTOT = NX + NP + NR;   // 227840

  split_all_kernel<<<(NTOT + 255) / 256, 256, 0, stream>>>(x, proj, rpe, xh, xl, ph, pl, rh, rl);

  dim3 gG(16, 26);  // 1024/64 cols, ceil(808/32) rows
  split_kernel<<<NW / 256, 256, 0, stream>>>(Wq, Wh, Wl, NW);
  gemm_split<1><<<gG, 256, 0, stream>>>(xh, xl, Wh, Wl, bq, nullptr, qh, ql, BL);

  split_kernel<<<NW / 256, 256, 0, stream>>>(Wv, Wh, Wl, NW);
  gemm_split<0><<<gG, 256, 0, stream>>>(xh, xl, Wh, Wl, bv, v, nullptr, nullptr, BL);

  vsum_kernel<<<BH, DH, 0, stream>>>(v, vsm);
  qf_kernel<<<RR / 32, 256, 0, stream>>>(qh, ql, ph, pl, rh, rl, rpe, fd);
  out_kernel<<<dim3((L + 1) / 2, BH), 256, 0, stream>>>(fd, v, vsm, qh, ql);

  split_kernel<<<NW / 256, 256, 0, stream>>>(Wo, Wh, Wl, NW);
  gemm_split<0><<<gG, 256, 0, stream>>>(qh, ql, Wh, Wl, bo, (float*)d_out, nullptr, nullptr, BL);
}

// Round 4
// 92.491 us; speedup vs baseline: 4.0306x; 2.2012x over previous
//
#include <hip/hip_runtime.h>
#include <math.h>

namespace {

typedef __bf16 bf16_t;
typedef bf16_t bf16x8 __attribute__((ext_vector_type(8)));
typedef bf16_t bf16x4 __attribute__((ext_vector_type(4)));
typedef float f32x4 __attribute__((ext_vector_type(4)));

constexpr int B = 8, L = 101, DIM = 1024, H = 8, DH = 128, MF = 621, MFP = 640;
constexpr int BL = B * L;    // 808
constexpr int BLP = 832;     // padded rows for GEMM A
constexpr int BH = B * H;    // 64
constexpr int RR = BL * H;   // 6464

constexpr float DN    = 0.29730177875068026f;   // 128^-0.25
constexpr float DN2   = 0.08838834764831845f;   // 128^-0.5
constexpr float RATIO = 0.04012861672f;         // 621^-0.5
constexpr float EPS   = 1e-4f;

// split_all segment sizes (bf16x4 / float4 units)
constexpr int NX = BL * DIM / 4;    // 206848
constexpr int NP = MFP * 32;        // 20480
constexpr int NR = 16 * DH / 4;     // 512
constexpr int NW = DIM * DIM / 4;   // 262144
constexpr int NZ = 4 * (BLP - BL) * DIM / 4;  // 24576 pad-zero units (xh,xl,qh,ql)
constexpr int NTOT = NX + NP + NR + 3 * NW + NZ;

__device__ __forceinline__ f32x4 mfma16(bf16x8 a, bf16x8 b, f32x4 c) {
  return __builtin_amdgcn_mfma_f32_16x16x32_bf16(a, b, c, 0, 0, 0);
}

__device__ __forceinline__ void split2(float f, bf16_t& h, bf16_t& l) {
  h = (bf16_t)f;
  l = (bf16_t)(f - (float)h);
}

__device__ __forceinline__ void gload_lds16(const bf16_t* g, bf16_t* l) {
  __builtin_amdgcn_global_load_lds(
      (const __attribute__((address_space(1))) void*)g,
      (__attribute__((address_space(3))) void*)l, 16, 0, 0);
}

// ---------- one-shot split of everything ----------
__global__ __launch_bounds__(256) void split_all(const float* __restrict__ x,
                                                 const float* __restrict__ proj,
                                                 const float* __restrict__ rpe,
                                                 const float* __restrict__ Wq,
                                                 const float* __restrict__ Wv,
                                                 const float* __restrict__ Wo,
                                                 bf16_t* __restrict__ xh, bf16_t* __restrict__ xl,
                                                 bf16_t* __restrict__ ph, bf16_t* __restrict__ pl,
                                                 bf16_t* __restrict__ rh, bf16_t* __restrict__ rl,
                                                 bf16_t* __restrict__ Wh, bf16_t* __restrict__ Wl,
                                                 bf16_t* __restrict__ Woh, bf16_t* __restrict__ Wol,
                                                 bf16_t* __restrict__ qh, bf16_t* __restrict__ ql) {
  const int u = blockIdx.x * 256 + threadIdx.x;
  if (u >= NTOT) return;
  auto emit = [](const float* s4, float sc, bf16_t* dh, bf16_t* dl, size_t off) {
    float4 f = *(const float4*)s4;
    bf16x4 hv, lv; bf16_t h, l;
    split2(f.x * sc, h, l); hv[0] = h; lv[0] = l;
    split2(f.y * sc, h, l); hv[1] = h; lv[1] = l;
    split2(f.z * sc, h, l); hv[2] = h; lv[2] = l;
    split2(f.w * sc, h, l); hv[3] = h; lv[3] = l;
    *(bf16x4*)(dh + off) = hv;
    *(bf16x4*)(dl + off) = lv;
  };
  int t = u;
  if (t < NX) { emit(x + (size_t)t * 4, 1.f, xh, xl, (size_t)t * 4); return; }
  t -= NX;
  if (t < NP) {
    bf16x4 z = {};
    if ((t >> 5) < MF) emit(proj + (size_t)t * 4, DN, ph, pl, (size_t)t * 4);
    else { *(bf16x4*)(ph + (size_t)t * 4) = z; *(bf16x4*)(pl + (size_t)t * 4) = z; }
    return;
  }
  t -= NP;
  if (t < NR) {
    bf16x4 z = {};
    if (t < 5 * DH / 4) emit(rpe + (size_t)t * 4, 1.f, rh, rl, (size_t)t * 4);
    else { *(bf16x4*)(rh + (size_t)t * 4) = z; *(bf16x4*)(rl + (size_t)t * 4) = z; }
    return;
  }
  t -= NR;
  if (t < NW) { emit(Wq + (size_t)t * 4, 1.f, Wh, Wl, (size_t)t * 4); return; }
  t -= NW;
  if (t < NW) { emit(Wv + (size_t)t * 4, 1.f, Wh, Wl, (size_t)(t + NW) * 4); return; }
  t -= NW;
  if (t < NW) { emit(Wo + (size_t)t * 4, 1.f, Woh, Wol, (size_t)t * 4); return; }
  t -= NW;
  {  // zero pads rows 808..831 of xh,xl,qh,ql
    const int buf = t / 6144, o = t % 6144;
    bf16_t* dst = (buf == 0) ? xh : (buf == 1) ? xl : (buf == 2) ? qh : ql;
    bf16x4 z = {};
    *(bf16x4*)(dst + (size_t)BL * DIM + (size_t)o * 4) = z;
  }
}

// ---------- LDS-staged split-bf16 MFMA GEMM ----------
// Tile 64x64, BK=32, 4 waves (2x2 of 32x32), double-buffered LDS via global_load_lds.
// MODE 0: C = f32 (bias0).  MODE 1 (qv): col<1024 -> bf16 split q (bias0); col>=1024 -> f32 v (bias1).
template<int MODE>
__global__ __launch_bounds__(256) void gemm_lds(const bf16_t* __restrict__ Ah,
                                                const bf16_t* __restrict__ Al,
                                                const bf16_t* __restrict__ Bh,
                                                const bf16_t* __restrict__ Bl,
                                                const float* __restrict__ bias0,
                                                const float* __restrict__ bias1,
                                                float* __restrict__ Cf,
                                                bf16_t* __restrict__ Ch,
                                                bf16_t* __restrict__ Cl, int M) {
  constexpr int K = 1024, NK = 32;
  __shared__ bf16_t lds[2][4][64 * 32];   // [dbuf][Ah,Al,Bh,Bl][row*32+col]
  const int tid = threadIdx.x;
  const int w = tid >> 6, lane = tid & 63;
  const int wr = w >> 1, wc = w & 1;
  const int l15 = lane & 15, l4 = lane >> 4;
  const int rowBase = blockIdx.y * 64, colBase = blockIdx.x * 64;
  // staging: wave w owns tile w (0:Ah 1:Al 2:Bh 3:Bl)
  const bf16_t* src = (w == 0) ? Ah : (w == 1) ? Al : (w == 2) ? Bh : Bl;
  const int gbase = (w < 2) ? rowBase : colBase;
  const int r16 = lane >> 2;
  const int cs = (lane & 3) ^ (r16 & 3);            // pre-swizzled source col16
  const bf16_t* srcL = src + (size_t)(gbase + r16) * K + cs * 8;
  auto STAGE = [&](int bf, int k0) {
#pragma unroll
    for (int j = 0; j < 4; ++j)
      gload_lds16(srcL + (size_t)(16 * j) * K + k0, &lds[bf][w][j * 512]);
  };
  // ds_read offsets (swizzled): row&3 == l15&3 for all four fragment rows
  const int cX = (l4 ^ (l15 & 3)) * 8;
  const int ar0 = (wr * 32 + l15) * 32 + cX, ar1 = ar0 + 16 * 32;
  const int br0 = (wc * 32 + l15) * 32 + cX, br1 = br0 + 16 * 32;
  f32x4 acc[2][2] = {};
  STAGE(0, 0);
  __syncthreads();
  int bf = 0;
  for (int ks = 0; ks < NK; ++ks) {
    if (ks + 1 < NK) STAGE(bf ^ 1, (ks + 1) * 32);
    bf16x8 a0h = *(const bf16x8*)&lds[bf][0][ar0];
    bf16x8 a0l = *(const bf16x8*)&lds[bf][1][ar0];
    bf16x8 a1h = *(const bf16x8*)&lds[bf][0][ar1];
    bf16x8 a1l = *(const bf16x8*)&lds[bf][1][ar1];
    bf16x8 b0h = *(const bf16x8*)&lds[bf][2][br0];
    bf16x8 b0l = *(const bf16x8*)&lds[bf][3][br0];
    bf16x8 b1h = *(const bf16x8*)&lds[bf][2][br1];
    bf16x8 b1l = *(const bf16x8*)&lds[bf][3][br1];
    acc[0][0] = mfma16(a0h, b0h, acc[0][0]);
    acc[0][0] = mfma16(a0l, b0h, acc[0][0]);
    acc[0][0] = mfma16(a0h, b0l, acc[0][0]);
    acc[0][1] = mfma16(a0h, b1h, acc[0][1]);
    acc[0][1] = mfma16(a0l, b1h, acc[0][1]);
    acc[0][1] = mfma16(a0h, b1l, acc[0][1]);
    acc[1][0] = mfma16(a1h, b0h, acc[1][0]);
    acc[1][0] = mfma16(a1l, b0h, acc[1][0]);
    acc[1][0] = mfma16(a1h, b0l, acc[1][0]);
    acc[1][1] = mfma16(a1h, b1h, acc[1][1]);
    acc[1][1] = mfma16(a1l, b1h, acc[1][1]);
    acc[1][1] = mfma16(a1h, b1l, acc[1][1]);
    __syncthreads();
    bf ^= 1;
  }
#pragma unroll
  for (int ni = 0; ni < 2; ++ni) {
    const int col = colBase + wc * 32 + ni * 16 + l15;
#pragma unroll
    for (int mi = 0; mi < 2; ++mi) {
#pragma unroll
      for (int r2 = 0; r2 < 4; ++r2) {
        const int row = rowBase + wr * 32 + mi * 16 + l4 * 4 + r2;
        if (row < M) {
          if (MODE == 0) {
            Cf[(size_t)row * 1024 + col] = acc[mi][ni][r2] + bias0[col];
          } else {
            if (col < 1024) {
              float val = acc[mi][ni][r2] + bias0[col];
              bf16_t h, lo; split2(val, h, lo);
              Ch[(size_t)row * 1024 + col] = h;
              Cl[(size_t)row * 1024 + col] = lo;
            } else {
              Cf[(size_t)row * 1024 + (col - 1024)] = acc[mi][ni][r2] + bias1[col - 1024];
            }
          }
        }
      }
    }
  }
}

// ---------- fused: dd-GEMM + rf-GEMM + maxes + exp + 5 reductions ----------
__global__ __launch_bounds__(256) void qf_kernel(const bf16_t* __restrict__ qh,
                                                 const bf16_t* __restrict__ ql,
                                                 const bf16_t* __restrict__ ph,
                                                 const bf16_t* __restrict__ pl,
                                                 const bf16_t* __restrict__ rh,
                                                 const bf16_t* __restrict__ rl,
                                                 const float* __restrict__ rpe,
                                                 float* __restrict__ fd) {
  __shared__ float rfs[5][MFP];
  __shared__ float diag[32];
  __shared__ float diag5v[8];
  __shared__ float mxs[4][32];
  __shared__ float mxAll[32];
  __shared__ float mxrf[4];
  __shared__ float sred[4][32][5];
  const int tid = threadIdx.x;
  const int r0 = blockIdx.x * 32;
  {
    const int row = tid >> 3, ch = tid & 7;
    const size_t base = (size_t)(r0 + row) * DH + ch * 16;
    float s = 0.f;
#pragma unroll
    for (int t = 0; t < 2; ++t) {
      bf16x8 vh = *(const bf16x8*)(qh + base + t * 8);
      bf16x8 vl = *(const bf16x8*)(ql + base + t * 8);
#pragma unroll
      for (int e = 0; e < 8; ++e) {
        float f = (float)vh[e] + (float)vl[e];
        s += f * f;
      }
    }
    s += __shfl_xor(s, 1, 64); s += __shfl_xor(s, 2, 64); s += __shfl_xor(s, 4, 64);
    if (ch == 0) diag[row] = (0.5f * DN2) * s;
  }
  if (tid < 40) {
    const int row = tid >> 3, ch = tid & 7;
    float s = 0.f;
#pragma unroll
    for (int e = 0; e < 16; ++e) {
      float f = rpe[row * DH + ch * 16 + e];
      s += f * f;
    }
    s += __shfl_xor(s, 1, 64); s += __shfl_xor(s, 2, 64); s += __shfl_xor(s, 4, 64);
    if (ch == 0) diag5v[row] = (0.5f * DN2) * s;
  }
  const int w = tid >> 6, lane = tid & 63, l15 = lane & 15, l4 = lane >> 4;
  const int nb = w * 160;
  f32x4 acc[2][10] = {};
  f32x4 accr[10] = {};
  const size_t a0 = (size_t)(r0 + l15) * DH + l4 * 8;
  const size_t a1 = a0 + (size_t)16 * DH;
  const size_t ar = (size_t)l15 * DH + l4 * 8;
#pragma unroll
  for (int ks = 0; ks < 4; ++ks) {
    const int k0 = ks * 32;
    bf16x8 a0h = *(const bf16x8*)(qh + a0 + k0);
    bf16x8 a0l = *(const bf16x8*)(ql + a0 + k0);
    bf16x8 a1h = *(const bf16x8*)(qh + a1 + k0);
    bf16x8 a1l = *(const bf16x8*)(ql + a1 + k0);
    bf16x8 arh = *(const bf16x8*)(rh + ar + k0);
    bf16x8 arl = *(const bf16x8*)(rl + ar + k0);
#pragma unroll
    for (int ni = 0; ni < 10; ++ni) {
      const size_t bo = (size_t)(nb + ni * 16 + l15) * DH + k0 + l4 * 8;
      bf16x8 bh = *(const bf16x8*)(ph + bo);
      bf16x8 bl = *(const bf16x8*)(pl + bo);
      acc[0][ni] = mfma16(a0h, bh, acc[0][ni]);
      acc[0][ni] = mfma16(a0l, bh, acc[0][ni]);
      acc[0][ni] = mfma16(a0h, bl, acc[0][ni]);
      acc[1][ni] = mfma16(a1h, bh, acc[1][ni]);
      acc[1][ni] = mfma16(a1l, bh, acc[1][ni]);
      acc[1][ni] = mfma16(a1h, bl, acc[1][ni]);
      accr[ni]   = mfma16(arh, bh, accr[ni]);
      accr[ni]   = mfma16(arl, bh, accr[ni]);
      accr[ni]   = mfma16(arh, bl, accr[ni]);
    }
  }
  float pm[2][4];
#pragma unroll
  for (int mi = 0; mi < 2; ++mi)
#pragma unroll
    for (int r2 = 0; r2 < 4; ++r2) {
      float m = -3.4e38f;
#pragma unroll
      for (int ni = 0; ni < 10; ++ni) {
        const int col = nb + ni * 16 + l15;
        float vv = (col < MF) ? acc[mi][ni][r2] : -3.4e38f;
        m = fmaxf(m, vv);
      }
      pm[mi][r2] = m;
    }
#pragma unroll
  for (int mask = 1; mask <= 8; mask <<= 1)
#pragma unroll
    for (int mi = 0; mi < 2; ++mi)
#pragma unroll
      for (int r2 = 0; r2 < 4; ++r2)
        pm[mi][r2] = fmaxf(pm[mi][r2], __shfl_xor(pm[mi][r2], mask, 64));
  if (l15 == 0) {
#pragma unroll
    for (int mi = 0; mi < 2; ++mi)
#pragma unroll
      for (int r2 = 0; r2 < 4; ++r2)
        mxs[w][mi * 16 + l4 * 4 + r2] = pm[mi][r2];
  }
  {
    float m = -3.4e38f;
#pragma unroll
    for (int ni = 0; ni < 10; ++ni) {
      const int col = nb + ni * 16 + l15;
#pragma unroll
      for (int r2 = 0; r2 < 4; ++r2) {
        const int row = l4 * 4 + r2;
        if (row < 5 && col < MF) m = fmaxf(m, accr[ni][r2]);
      }
    }
#pragma unroll
    for (int mask = 1; mask <= 32; mask <<= 1) m = fmaxf(m, __shfl_xor(m, mask, 64));
    if (lane == 0) mxrf[w] = m;
  }
  __syncthreads();
  {
    const float mxR = fmaxf(fmaxf(mxrf[0], mxrf[1]), fmaxf(mxrf[2], mxrf[3]));
#pragma unroll
    for (int ni = 0; ni < 10; ++ni) {
      const int col = nb + ni * 16 + l15;
#pragma unroll
      for (int r2 = 0; r2 < 4; ++r2) {
        const int row = l4 * 4 + r2;
        if (row < 5) {
          float val = (col < MF)
              ? RATIO * (__expf(accr[ni][r2] - diag5v[row] - mxR) + EPS) : 0.f;
          rfs[row][col] = val;
        }
      }
    }
  }
  if (tid < 32)
    mxAll[tid] = fmaxf(fmaxf(mxs[0][tid], mxs[1][tid]), fmaxf(mxs[2][tid], mxs[3][tid]));
  __syncthreads();
  for (int i = tid; i < 4 * MFP; i += 256) rfs[i / MFP][i % MFP] -= rfs[4][i % MFP];
  __syncthreads();
  float s[2][4][5] = {};
#pragma unroll
  for (int mi = 0; mi < 2; ++mi)
#pragma unroll
    for (int r2 = 0; r2 < 4; ++r2) {
      const int row = mi * 16 + l4 * 4 + r2;
      const float sub = diag[row] + mxAll[row];
#pragma unroll
      for (int ni = 0; ni < 10; ++ni) {
        const int col = nb + ni * 16 + l15;
        const float qfv = RATIO * (__expf(acc[mi][ni][r2] - sub) + EPS);
#pragma unroll
        for (int c = 0; c < 5; ++c) s[mi][r2][c] += qfv * rfs[c][col];
      }
    }
#pragma unroll
  for (int mask = 1; mask <= 8; mask <<= 1)
#pragma unroll
    for (int mi = 0; mi < 2; ++mi)
#pragma unroll
      for (int r2 = 0; r2 < 4; ++r2)
#pragma unroll
        for (int c = 0; c < 5; ++c)
          s[mi][r2][c] += __shfl_xor(s[mi][r2][c], mask, 64);
  if (l15 == 0) {
#pragma unroll
    for (int mi = 0; mi < 2; ++mi)
#pragma unroll
      for (int r2 = 0; r2 < 4; ++r2)
#pragma unroll
        for (int c = 0; c < 5; ++c)
          sred[w][mi * 16 + l4 * 4 + r2][c] = s[mi][r2][c];
  }
  __syncthreads();
  if (tid < 160) {
    const int row = tid / 5, c = tid % 5;
    fd[(size_t)(r0 + row) * 8 + c] =
        sred[0][row][c] + sred[1][row][c] + sred[2][row][c] + sred[3][row][c];
  }
}

// ---------- v_sum over L, 4-way split ----------
__global__ __launch_bounds__(128) void vsum_kernel(const float* __restrict__ v,
                                                   float* __restrict__ vsum4) {
  const int bh = blockIdx.x, s = blockIdx.y, d = threadIdx.x;
  const int b = bh >> 3, h = bh & 7;
  const int lo = s * 26, hi = (lo + 26 < L) ? lo + 26 : L;
  const float* base = v + (size_t)(b * L) * DIM + h * DH + d;
  float sum = 0.f;
#pragma unroll 8
  for (int l = lo; l < hi; ++l) sum += base[(size_t)l * DIM];
  vsum4[((size_t)s * BH + bh) * DH + d] = sum;
}

// ---------- gather + normalize + bf16-split of attn ----------
__global__ __launch_bounds__(256) void out_kernel(const float* __restrict__ fd,
                                                  const float* __restrict__ v,
                                                  const float* __restrict__ vsum4,
                                                  bf16_t* __restrict__ attnh,
                                                  bf16_t* __restrict__ attnl) {
  const int tid = threadIdx.x;
  const int sub = tid >> 7, d = tid & 127;
  const int bh = blockIdx.y, b = bh >> 3, h = bh & 7;
  const int l = blockIdx.x * 2 + sub;
  if (l >= L) return;
  const size_t r = (size_t)(b * L + l) * H + h;
  const float q0 = fd[r * 8 + 0], q1 = fd[r * 8 + 1], q2 = fd[r * 8 + 2],
              q3 = fd[r * 8 + 3], sM = fd[r * 8 + 4];
  const float vs = vsum4[(size_t)bh * DH + d] + vsum4[((size_t)BH + bh) * DH + d] +
                   vsum4[((size_t)2 * BH + bh) * DH + d] + vsum4[((size_t)3 * BH + bh) * DH + d];
  float o = sM * vs;
  float c0 = 0, c1 = 0, c2 = 0, c3 = 0;
  const int xo = (l < 100) ? (l % 10) : 0;
  const int yo = (l < 100) ? (l / 10) : 10;
#pragma unroll
  for (int k = 0; k < 49; ++k) {
    const int dx = (k % 7) - 3, dy = (k / 7) - 3;
    const int xp = xo + dx, yp = yo + dy;
    const int df = (dx < 0 ? -dx : dx) + (dy < 0 ? -dy : dy);
    if (xp >= 0 && xp < 10 && yp >= 0 && yp < 10 && df < 4) {
      float qq;
      if (df == 0)      { c0 += 1.f; qq = q0; }
      else if (df == 1) { c1 += 1.f; qq = q1; }
      else if (df == 2) { c2 += 1.f; qq = q2; }
      else              { c3 += 1.f; qq = q3; }
      const int pos = l + dx + 10 * dy;
      o += qq * v[(size_t)(b * L + pos) * DIM + h * DH + d];
    }
  }
  const float D = c0 * q0 + c1 * q1 + c2 * q2 + c3 * q3 + (float)L * sM;
  const float val = o / D;
  bf16_t hi, lo; split2(val, hi, lo);
  const size_t oi = (size_t)(b * L + l) * DIM + h * DH + d;
  attnh[oi] = hi;
  attnl[oi] = lo;
}

}  // namespace

extern "C" void kernel_launch(void* const* d_in, const int* in_sizes, int n_in,
                              void* d_out, int out_size, void* d_ws, size_t ws_size,
                              hipStream_t stream) {
  const float* x    = (const float*)d_in[0];
  const float* Wq   = (const float*)d_in[1];
  const float* bq   = (const float*)d_in[2];
  const float* Wv   = (const float*)d_in[3];
  const float* bv   = (const float*)d_in[4];
  const float* rpe  = (const float*)d_in[5];
  const float* proj = (const float*)d_in[6];
  const float* Wo   = (const float*)d_in[7];
  const float* bo   = (const float*)d_in[8];

  char* p = (char*)d_ws;
  auto alloc = [&](size_t bytes) { char* r = p; p += (bytes + 255) & ~255ull; return r; };
  bf16_t* xh  = (bf16_t*)alloc((size_t)BLP * DIM * 2);
  bf16_t* xl  = (bf16_t*)alloc((size_t)BLP * DIM * 2);
  bf16_t* Wh  = (bf16_t*)alloc((size_t)2 * DIM * DIM * 2);  // Wq rows 0..1023, Wv rows 1024..2047
  bf16_t* Wl  = (bf16_t*)alloc((size_t)2 * DIM * DIM * 2);
  bf16_t* Woh = (bf16_t*)alloc((size_t)DIM * DIM * 2);
  bf16_t* Wol = (bf16_t*)alloc((size_t)DIM * DIM * 2);
  bf16_t* ph  = (bf16_t*)alloc((size_t)MFP * DH * 2);
  bf16_t* pl  = (bf16_t*)alloc((size_t)MFP * DH * 2);
  bf16_t* rh  = (bf16_t*)alloc((size_t)16 * DH * 2);
  bf16_t* rl  = (bf16_t*)alloc((size_t)16 * DH * 2);
  bf16_t* qh  = (bf16_t*)alloc((size_t)BLP * DIM * 2);   // q, later attn
  bf16_t* ql  = (bf16_t*)alloc((size_t)BLP * DIM * 2);
  float*  v   = (float*)alloc((size_t)BL * DIM * 4);
  float*  fd  = (float*)alloc((size_t)RR * 8 * 4);
  float*  vs4 = (float*)alloc((size_t)4 * BH * DH * 4);

  split_all<<<(NTOT + 255) / 256, 256, 0, stream>>>(x, proj, rpe, Wq, Wv, Wo,
                                                    xh, xl, ph, pl, rh, rl,
                                                    Wh, Wl, Woh, Wol, qh, ql);
  // fused q+v projection: N=2048
  gemm_lds<1><<<dim3(32, 13), 256, 0, stream>>>(xh, xl, Wh, Wl, bq, bv, v, qh, ql, BL);
  vsum_kernel<<<dim3(BH, 4), 128, 0, stream>>>(v, vs4);
  qf_kernel<<<RR / 32, 256, 0, stream>>>(qh, ql, ph, pl, rh, rl, rpe, fd);
  out_kernel<<<dim3((L + 1) / 2, BH), 256, 0, stream>>>(fd, v, vs4, qh, ql);
  gemm_lds<0><<<dim3(16, 13), 256, 0, stream>>>(qh, ql, Woh, Wol, bo, nullptr,
                                                (float*)d_out, nullptr, nullptr, BL);
}